// Round 7
// baseline (112.909 us; speedup 1.0000x reference)
//
#include <hip/hip_runtime.h>
#include <math.h>

#define N_OCT  16
#define NS     32768
#define TPB    256
#define NSPLIT 4                  // chunks per row
#define CHUNK  (NS / NSPLIT)      // 8192 samples per block
#define SPT    (CHUNK / TPB)      // 32 samples per thread
#define N_BE   512                // B*E = 8*64
#define NBLK   (N_BE * NSPLIT)    // 2048 blocks

typedef float v2f __attribute__((ext_vector_type(2)));
typedef _Float16 h4 __attribute__((ext_vector_type(4)));

static __device__ __forceinline__ v2f fma2(v2f a, v2f b, v2f c) {
    return __builtin_elementwise_fma(a, b, c);
}

// ws layout: [0, 32MiB) fp16 stage[N_BE][NS]; [32MiB, +8KiB) float maxes[2048].
// Every byte read is written in the same launch (poison-proof).
#define WS_STAGE(ws) ((_Float16*)(ws))
#define WS_MAX(ws)   ((float*)((char*)(ws) + (size_t)N_BE * NS * 2))

// R7. R6 failed at absmax 0.039 (thr 0.02): the fp32 Dekker-twoprod seed
// path lost its exact residual (compiler legally reassociates/CSEs
// fma(n,rh,-hi) against hi=n*rh under the harness flags) -> seed phase err
// ~2^-10 rev, amplified by the recurrence's 1/sin(theta_step) seed-noise
// factor. LESSON: never build precision on FP idioms the optimizer can
// destroy. Fix: INTEGER Q32 fixed-point phase, immune to FP transforms:
//   frac(n*r) = (uint32)((uint32)n * r_q32) * 2^-32,  r_q32 = round(r*2^32)
// (low 32 bits of the product = exact modular arithmetic; signed n wraps
// correctly in two's complement). Error: frequency quantization 2^-33
// rev/sample is LINEAR in n -> consistent across both seeds -> no 1/sin
// amplification (2nd order); independent per-seed noise is only the uint->
// float convert (2^-25 rev), below the v_sin_f32 noise R1-R4 already
// tolerated at absmax 0.015625.
// Structure (untimed R6 hypothesis, rides along): ONE recurrence pass total.
//   K1: chunk recurrence once, stage unnormalized fp16 to global ws (fp16
//       staging proven in R1: same 0.015625 absmax as fp32 paths), chunk max
//       to ws. No fp64 anywhere in the wide kernel.
//   K2: pure memory: fp16 stage -> *norm -> fp32 out. Stage reads likely
//       L2-hit (same bid->XCD round-robin as K1's writes).
// Balance: 2048 blocks = 8 row-draws/CU (R3: 1 block/row was imbalance-
// bound at 21% occupancy). Dead-octave skip kept (nyquist zeroes a SUFFIX;
// f0s non-decreasing in octave); template variants {2,4,8}, dead pairs have
// amp=0 so padding is bit-exact.

static __device__ __forceinline__ void make_consts(
    int be, int t,
    const float* __restrict__ f0_in, const float* __restrict__ dc_in,
    const float* __restrict__ fs_in,
    unsigned int* __restrict__ sRQ,
    float* __restrict__ sCH, float* __restrict__ sCL,
    float* __restrict__ sAMP, int* __restrict__ sLive)
{
    if (t < N_OCT) {
        const int o = t;
        const float f0a = fabsf(f0_in[be]);
        const float dc  = dc_in[be];
        const float fs  = fs_in[be];

        const float MINF = (float)(20.0 / 11025.0);
        const float FRNG = (float)(3000.0 / 11025.0 - 20.0 / 11025.0);

        // double sigmoid (reference applies sigmoid twice), decay ladder
        const float s1    = 1.0f / (1.0f + __expf(-dc));
        const float dv    = 1.0f / (1.0f + __expf(-s1));
        const float decay = 0.01f + dv * 0.9801f;          // (1-0.01)*0.99
        const float logd  = __logf(decay + 1e-12f);
        const float f0r   = (MINF + f0a * FRNG) * 3.14159274101257324f;

        // sequential float cumsum, bit-matching the reference's jnp.cumsum
        float cl = 0.f, cf = 0.f;
        for (int i = 0; i <= o; ++i) { cl += logd; cf += fs; }
        float ed  = __expf(cl);                            // decay^(o+1)
        float f0s = f0r * cf;                              // rad/sample
        float a   = ed;
        const bool live = (f0s < 1.0f);                    // nyquist cutoff
        if (!live) { a = 0.0f; f0s = 0.0f; }

        unsigned long long lm = __ballot(live);
        if (o == 0) *sLive = __popcll(lm);

        const double inv2pi = 0.15915494309189535;
        const double r = (double)f0s * inv2pi;             // revolutions/sample
        // Q32 fixed-point frequency (r < 0.16, no overflow). fp64 only in
        // this 16-lane prologue.
        const unsigned int rq = (unsigned int)llrint(r * 4294967296.0);

        // c2 = 2*cos(TPB*theta) as double-float pair (single-float c2 is
        // ill-conditioned when TPB*theta mod 2pi ~ 0/pi)
        double drev = r * (double)TPB;
        drev -= floor(drev);
        double c2d = 2.0 * cos(drev * 6.283185307179586);
        float  ch  = (float)c2d;

        sRQ[o]  = rq;
        sCH[o]  = ch;
        sCL[o]  = (float)(c2d - (double)ch);
        sAMP[o] = a;
    }
}

// phase in revolutions [0,1): exact modular Q32, compiler-proof integer math
static __device__ __forceinline__ float q32_phase(int n, unsigned int rq)
{
    const unsigned int frac = (unsigned int)n * rq;    // low 32 bits, exact mod
    return (float)frac * 2.3283064365386963e-10f;      // * 2^-32
}

// one recurrence pass over the chunk: stage fp16 to global, return lane max
template<int NP>
static __device__ __forceinline__ float body_stage(
    int base, int t,
    const unsigned int* __restrict__ sRQ,
    const float* __restrict__ sCH, const float* __restrict__ sCL,
    const float* __restrict__ sAMP,
    _Float16* __restrict__ stage)            // global, chunk-based
{
    v2f xp[NP], xc[NP], c2h[NP], c2l[NP];

    // seed: y[s] = amp*sin(2pi*frac((s+1)*r)) at s = base+t, s = base+t-TPB
    const int n1 = base + t + 1;
    const int n0 = base + t + 1 - TPB;
    #pragma unroll
    for (int o = 0; o < 2 * NP; ++o) {
        const unsigned int rq = sRQ[o];
        const float a = sAMP[o];             // 0 for dead octaves
        float xcur  = a * __builtin_amdgcn_sinf(q32_phase(n1, rq));
        float xprev = a * __builtin_amdgcn_sinf(q32_phase(n0, rq));
        const int j = o >> 1;
        if ((o & 1) == 0) {
            xc[j].x = xcur;    xp[j].x = xprev;
            c2h[j].x = sCH[o]; c2l[j].x = sCL[o];
        } else {
            xc[j].y = xcur;    xp[j].y = xprev;
            c2h[j].y = sCH[o]; c2l[j].y = sCL[o];
        }
    }

    float lmax = 0.0f;
    #pragma unroll 4
    for (int k = 0; k < SPT; ++k) {
        v2f acc2 = (v2f)(0.0f);
        #pragma unroll
        for (int j = 0; j < NP; ++j) {
            acc2 += xc[j];                   // amp pre-folded in state
            v2f xn = fma2(c2h[j], xc[j], fma2(c2l[j], xc[j], -xp[j]));
            xp[j] = xc[j];
            xc[j] = xn;
        }
        const float acc = acc2.x + acc2.y;
        stage[k * TPB + t] = (_Float16)acc;  // 2B/lane coalesced global store
        lmax = fmaxf(lmax, fabsf(acc));
    }
    return lmax;
}

__global__ __launch_bounds__(TPB)
void f0res_stage_k(const float* __restrict__ f0_in,
                   const float* __restrict__ dc_in,
                   const float* __restrict__ fs_in,
                   void* __restrict__ ws)
{
    __shared__ unsigned int sRQ[N_OCT];
    __shared__ float sCH[N_OCT], sCL[N_OCT], sAMP[N_OCT];
    __shared__ float wmax[TPB / 64];
    __shared__ int   sLive;

    const int bid = blockIdx.x;
    const int be  = bid >> 2;                          // row
    const int q   = bid & 3;                           // chunk
    const int t   = threadIdx.x;
    const int base = q * CHUNK;

    make_consts(be, t, f0_in, dc_in, fs_in, sRQ, sCH, sCL, sAMP, &sLive);
    __syncthreads();

    const int L  = sLive;
    _Float16* __restrict__ stage = WS_STAGE(ws) + (size_t)be * NS + base;

    float lmax = 0.0f;
    if (L == 0) {
        #pragma unroll
        for (int k = 0; k < SPT; ++k) stage[k * TPB + t] = (_Float16)0.0f;
    } else if (L <= 4) {
        lmax = body_stage<2>(base, t, sRQ, sCH, sCL, sAMP, stage);
    } else if (L <= 8) {
        lmax = body_stage<4>(base, t, sRQ, sCH, sCL, sAMP, stage);
    } else {
        lmax = body_stage<8>(base, t, sRQ, sCH, sCL, sAMP, stage);
    }

    // block max: wave shuffle then tiny LDS; one slot per block (no atomics)
    #pragma unroll
    for (int off = 32; off > 0; off >>= 1)
        lmax = fmaxf(lmax, __shfl_down(lmax, off, 64));
    if ((t & 63) == 0) wmax[t >> 6] = lmax;
    __syncthreads();
    if (t == 0) {
        float bmax = wmax[0];
        #pragma unroll
        for (int w = 1; w < TPB / 64; ++w) bmax = fmaxf(bmax, wmax[w]);
        WS_MAX(ws)[bid] = bmax;
    }
}

// K2: pure-memory normalize. fp16 stage -> fp32 out, norm folded.
__global__ __launch_bounds__(TPB)
void f0res_norm_k(const void* __restrict__ ws,
                  float* __restrict__ out)
{
    const int bid = blockIdx.x;
    const int be  = bid >> 2;
    const int q   = bid & 3;
    const int t   = threadIdx.x;

    const float* mx = WS_MAX(ws) + (be << 2);          // uniform scalar loads
    const float bmax = fmaxf(fmaxf(mx[0], mx[1]), fmaxf(mx[2], mx[3]));
    const float norm = 1.0f / (bmax + 1e-8f);

    const h4* __restrict__ src =
        (const h4*)(WS_STAGE(ws) + (size_t)be * NS + q * CHUNK);
    float4* __restrict__ dst = (float4*)(out + (size_t)be * NS + q * CHUNK);

    #pragma unroll
    for (int i = 0; i < CHUNK / 4 / TPB; ++i) {        // 8 iters
        const int idx = i * TPB + t;                   // h4/float4 index
        h4 v = src[idx];                               // 8B/lane coalesced
        float4 o;
        o.x = (float)v.x * norm; o.y = (float)v.y * norm;
        o.z = (float)v.z * norm; o.w = (float)v.w * norm;
        dst[idx] = o;                                  // 16B/lane coalesced
    }
}

extern "C" void kernel_launch(void* const* d_in, const int* in_sizes, int n_in,
                              void* d_out, int out_size, void* d_ws, size_t ws_size,
                              hipStream_t stream) {
    const float* f0 = (const float*)d_in[0];
    const float* dc = (const float*)d_in[1];
    const float* fs = (const float*)d_in[3];   // d_in[2] is "unused"
    float* out = (float*)d_out;

    hipLaunchKernelGGL(f0res_stage_k, dim3(NBLK), dim3(TPB), 0, stream,
                       f0, dc, fs, d_ws);
    hipLaunchKernelGGL(f0res_norm_k, dim3(NBLK), dim3(TPB), 0, stream,
                       d_ws, out);
}

// Round 8
// 99.704 us; speedup vs baseline: 1.1324x; 1.1324x over previous
//
#include <hip/hip_runtime.h>
#include <math.h>

#define N_OCT 16
#define NS    32768
#define TPB   512
#define SPT   (NS / TPB)   // 64 samples per thread
#define N_BE  512          // B*E = 8*64

typedef float v2f __attribute__((ext_vector_type(2)));
typedef _Float16 h4 __attribute__((ext_vector_type(4)));

static __device__ __forceinline__ v2f fma2(v2f a, v2f b, v2f c) {
    return __builtin_elementwise_fma(a, b, c);
}

// R8: best-of-all-rounds synthesis. Evidence ledger:
//  - R1 (single pass + fp16 LDS stage, 1 big kernel): ~36us kernel, best.
//  - R7 (single pass, global fp16 stage + norm kernel): ~44us combined --
//    the 32MiB stage round-trip + extra launch ate the single-pass gain.
//  - Model recalibration vs R2's VALUBusy: each v2f op costs ~5.6cyc
//    effective, NOT 2 -- scalarization + the xp=xc;xc=xn ROTATION MOVS
//    (4 movs per pair-step on top of 4 FMAs). Retro-predicts R1/R2/R7. 
//  - absmax = exactly 2^-6 for every passing numeric path => reference-
//    quantization floor, we have ~0.004 genuine headroom.
// Changes vs R1: (a) dead-octave skip (nyquist zeroes a SUFFIX since
// f0s = f0r*cumsum(fs) is non-decreasing; ~40% less work, bit-exact since
// dead amp=0), (b) Q32 integer fixed-point seeds (R7-proven: exact modular
// phase, compiler-proof, no fp64 in wide code; R6's fp32-twoprod was broken
// by FP reassociation -- never again), (c) UNROLL-BY-2 ROLE SWAP inner
// loop: step A writes next state into xp, step B writes into xc -- the
// rotation movs vanish (role alternation = register renaming), (d) consts
// computed by 16 lanes in-block (no setup dispatch).
// Occupancy: LDS 64KiB dynamic -> 2 blocks/CU (R1-verified residency).
// (512,1) launch bounds: R0-verified spill-free; loose bound costs nothing
// since LDS caps blocks/CU anyway.

static __device__ __forceinline__ void make_consts(
    int be, int t,
    const float* __restrict__ f0_in, const float* __restrict__ dc_in,
    const float* __restrict__ fs_in,
    unsigned int* __restrict__ sRQ,
    float* __restrict__ sCH, float* __restrict__ sCL,
    float* __restrict__ sAMP, int* __restrict__ sLive)
{
    if (t < N_OCT) {
        const int o = t;
        const float f0a = fabsf(f0_in[be]);
        const float dc  = dc_in[be];
        const float fs  = fs_in[be];

        const float MINF = (float)(20.0 / 11025.0);
        const float FRNG = (float)(3000.0 / 11025.0 - 20.0 / 11025.0);

        // double sigmoid (reference applies sigmoid twice), decay ladder
        const float s1    = 1.0f / (1.0f + __expf(-dc));
        const float dv    = 1.0f / (1.0f + __expf(-s1));
        const float decay = 0.01f + dv * 0.9801f;          // (1-0.01)*0.99
        const float logd  = __logf(decay + 1e-12f);
        const float f0r   = (MINF + f0a * FRNG) * 3.14159274101257324f;

        // sequential float cumsum, bit-matching the reference's jnp.cumsum
        float cl = 0.f, cf = 0.f;
        for (int i = 0; i <= o; ++i) { cl += logd; cf += fs; }
        float ed  = __expf(cl);                            // decay^(o+1)
        float f0s = f0r * cf;                              // rad/sample
        float a   = ed;
        const bool live = (f0s < 1.0f);                    // nyquist cutoff
        if (!live) { a = 0.0f; f0s = 0.0f; }

        unsigned long long lm = __ballot(live);
        if (o == 0) *sLive = __popcll(lm);

        const double inv2pi = 0.15915494309189535;
        const double r = (double)f0s * inv2pi;             // revolutions/sample
        // Q32 fixed-point frequency (r < 0.16). fp64 only in this 16-lane
        // prologue, hidden under the barrier.
        const unsigned int rq = (unsigned int)llrint(r * 4294967296.0);

        // c2 = 2*cos(TPB*theta) as double-float pair (single-float c2 is
        // ill-conditioned when TPB*theta mod 2pi ~ 0/pi)
        double drev = r * (double)TPB;
        drev -= floor(drev);
        double c2d = 2.0 * cos(drev * 6.283185307179586);
        float  ch  = (float)c2d;

        sRQ[o]  = rq;
        sCH[o]  = ch;
        sCL[o]  = (float)(c2d - (double)ch);
        sAMP[o] = a;
    }
}

// phase in revolutions [0,1): exact modular Q32, compiler-proof integer math.
// v_sin_f32 takes REVOLUTIONS (D = sin(S0*2pi)) -- R1-R7 verified.
static __device__ __forceinline__ float q32_phase(int n, unsigned int rq)
{
    const unsigned int frac = (unsigned int)n * rq;    // low 32 bits, exact mod
    return (float)frac * 2.3283064365386963e-10f;      // * 2^-32
}

// single recurrence pass: stage fp16 to LDS, return lane max.
// Inner loop unrolled by 2 with ROLE SWAP (A: next->xp, B: next->xc) so the
// compiler never emits state-rotation movs.
template<int NP>
static __device__ __forceinline__ float body_stage(
    int t,
    const unsigned int* __restrict__ sRQ,
    const float* __restrict__ sCH, const float* __restrict__ sCL,
    const float* __restrict__ sAMP,
    _Float16* __restrict__ smem)
{
    v2f xp[NP], xc[NP], c2h[NP], c2l[NP];

    // seed: y[s] = amp*sin(2pi*frac((s+1)*r)) at s = t and s = t-TPB
    const int n1 = t + 1;
    const int n0 = t + 1 - TPB;
    #pragma unroll
    for (int o = 0; o < 2 * NP; ++o) {
        const unsigned int rq = sRQ[o];
        const float a = sAMP[o];             // 0 for dead octaves
        float xcur  = a * __builtin_amdgcn_sinf(q32_phase(n1, rq));
        float xprev = a * __builtin_amdgcn_sinf(q32_phase(n0, rq));
        const int j = o >> 1;
        if ((o & 1) == 0) {
            xc[j].x = xcur;    xp[j].x = xprev;
            c2h[j].x = sCH[o]; c2l[j].x = sCL[o];
        } else {
            xc[j].y = xcur;    xp[j].y = xprev;
            c2h[j].y = sCH[o]; c2l[j].y = sCL[o];
        }
    }

    float lmax = 0.0f;
    #pragma unroll 2
    for (int k = 0; k < SPT; k += 2) {
        // step A: sample k from (prev=xp, cur=xc); next state -> xp
        v2f accA = (v2f)(0.0f);
        #pragma unroll
        for (int j = 0; j < NP; ++j) {
            accA += xc[j];
            xp[j] = fma2(c2h[j], xc[j], fma2(c2l[j], xc[j], -xp[j]));
        }
        // step B: sample k+1 from (prev=xc, cur=xp); next state -> xc
        v2f accB = (v2f)(0.0f);
        #pragma unroll
        for (int j = 0; j < NP; ++j) {
            accB += xp[j];
            xc[j] = fma2(c2h[j], xp[j], fma2(c2l[j], xp[j], -xc[j]));
        }
        const float a = accA.x + accA.y;
        const float b = accB.x + accB.y;
        smem[k * TPB + t]       = (_Float16)a;         // 2-way bank: free
        smem[(k + 1) * TPB + t] = (_Float16)b;
        lmax = fmaxf(lmax, fmaxf(fabsf(a), fabsf(b)));
    }
    return lmax;
}

__global__ __launch_bounds__(TPB, 1)
void f0res_kernel(const float* __restrict__ f0_in,
                  const float* __restrict__ dc_in,
                  const float* __restrict__ fs_in,
                  float* __restrict__ out)
{
    extern __shared__ _Float16 smem[];                 // NS halves = 64 KiB
    __shared__ unsigned int sRQ[N_OCT];
    __shared__ float sCH[N_OCT], sCL[N_OCT], sAMP[N_OCT];
    __shared__ float wmax[TPB / 64];
    __shared__ int   sLive;

    const int be = blockIdx.x;
    const int t  = threadIdx.x;

    make_consts(be, t, f0_in, dc_in, fs_in, sRQ, sCH, sCL, sAMP, &sLive);
    __syncthreads();

    const int L = sLive;
    float* __restrict__ orow = out + (size_t)be * NS;

    if (L == 0) {                                      // all-dead row: zeros
        #pragma unroll
        for (int k = 0; k < SPT; ++k) orow[k * TPB + t] = 0.0f;
        return;
    }

    float lmax;
    if (L <= 4)      lmax = body_stage<2>(t, sRQ, sCH, sCL, sAMP, smem);
    else if (L <= 8) lmax = body_stage<4>(t, sRQ, sCH, sCL, sAMP, smem);
    else             lmax = body_stage<8>(t, sRQ, sCH, sCL, sAMP, smem);

    // block max: wave shuffle then tiny LDS
    #pragma unroll
    for (int off = 32; off > 0; off >>= 1)
        lmax = fmaxf(lmax, __shfl_down(lmax, off, 64));
    if ((t & 63) == 0) wmax[t >> 6] = lmax;
    __syncthreads();
    float bmax = wmax[0];
    #pragma unroll
    for (int w = 1; w < TPB / 64; ++w) bmax = fmaxf(bmax, wmax[w]);

    const float norm = 1.0f / (bmax + 1e-8f);

    // LDS fp16 -> normalized fp32, coalesced float4 stores
    float4* __restrict__ out4 = (float4*)orow;
    #pragma unroll
    for (int i = 0; i < NS / 4 / TPB; ++i) {           // 16 float4/thread
        const int idx = i * TPB + t;                   // float4 index
        h4 v = *(const h4*)(smem + 4 * (size_t)idx);   // ds_read_b64, 8B align
        float4 o;
        o.x = (float)v.x * norm; o.y = (float)v.y * norm;
        o.z = (float)v.z * norm; o.w = (float)v.w * norm;
        out4[idx] = o;
    }
}

extern "C" void kernel_launch(void* const* d_in, const int* in_sizes, int n_in,
                              void* d_out, int out_size, void* d_ws, size_t ws_size,
                              hipStream_t stream) {
    const float* f0 = (const float*)d_in[0];
    const float* dc = (const float*)d_in[1];
    const float* fs = (const float*)d_in[3];   // d_in[2] is "unused"
    float* out = (float*)d_out;
    (void)d_ws; (void)ws_size;

    hipLaunchKernelGGL(f0res_kernel, dim3(N_BE), dim3(TPB),
                       NS * sizeof(_Float16), stream, f0, dc, fs, out);
}